// Round 4
// baseline (366.431 us; speedup 1.0000x reference)
//
#include <hip/hip_runtime.h>

#define NN 2
#define LL 4096
#define HH 12
#define DD 64
#define HD_ 768
#define M_TOT (NN * LL)   // 8192

typedef __bf16 bf16_t;
typedef _Float16 f16_t;
typedef __bf16 bf16x8 __attribute__((ext_vector_type(8)));
typedef __bf16 bf16x4 __attribute__((ext_vector_type(4)));
typedef _Float16 f16x2 __attribute__((ext_vector_type(2)));
typedef _Float16 f16x4 __attribute__((ext_vector_type(4)));
typedef _Float16 f16x8 __attribute__((ext_vector_type(8)));
typedef float floatx4 __attribute__((ext_vector_type(4)));

// softmax prescale folded into Q at the QKV GEMM: 1/sqrt(64) * log2(e)
#define QSCALE 0.1803368801111f

__device__ __forceinline__ void async_load16(const bf16_t* g, bf16_t* l) {
    __builtin_amdgcn_global_load_lds(
        (const __attribute__((address_space(1))) unsigned int*)(g),
        (__attribute__((address_space(3))) unsigned int*)(l),
        16, 0, 0);
}

__device__ __forceinline__ f16x2 pkrtz(float a, float b) {
    return __builtin_bit_cast(f16x2, __builtin_amdgcn_cvt_pkrtz(a, b));
}

// ---------------- fp32 -> bf16 convert (x) ---------------------------------
__global__ void cvt_kernel(const float* __restrict__ src, bf16_t* __restrict__ dst, int n4) {
    int i = blockIdx.x * blockDim.x + threadIdx.x;
    if (i < n4) {
        const float4 v = ((const float4*)src)[i];
        bf16_t* d = dst + (size_t)i * 4;
        d[0] = (bf16_t)v.x; d[1] = (bf16_t)v.y; d[2] = (bf16_t)v.z; d[3] = (bf16_t)v.w;
    }
}

// ------------- fp32 W (K x N) -> bf16 W^T (N x K), 4 weights fused ---------
struct WtArgs { const float* W[4]; bf16_t* Wt[4]; };
__global__ void cvt_wt_kernel(WtArgs a) {
    const int z = blockIdx.z;
    int id = blockIdx.x * 256 + threadIdx.x;
    int k = id / HD_;
    int n = id % HD_;
    a.Wt[z][(size_t)n * HD_ + k] = (bf16_t)a.W[z][id];
}

// ---------------- shared 64x64 GEMM tile core ------------------------------
__device__ __forceinline__ void gemm_tile64(
    const bf16_t* __restrict__ A, const bf16_t* __restrict__ Bt,
    bf16_t* As, bf16_t* Bs, int m0, int n0, floatx4 (&acc)[2][2])
{
    const int tid  = threadIdx.x;
    const int lane = tid & 63;
    const int quad = lane >> 4, l16 = lane & 15;
    const int wave = tid >> 6;
    const int wm = wave >> 1, wn = wave & 1;
    const int lrow = tid >> 2;
    const int lcol = (tid & 3) * 16;

    for (int kt = 0; kt < HD_; kt += 64) {
        __syncthreads();
        {
            const bf16_t* ga = A + (size_t)(m0 + lrow) * HD_ + kt + lcol;
            *(bf16x8*)&As[lrow * 72 + lcol]     = *(const bf16x8*)ga;
            *(bf16x8*)&As[lrow * 72 + lcol + 8] = *(const bf16x8*)(ga + 8);
            const bf16_t* gb = Bt + (size_t)(n0 + lrow) * HD_ + kt + lcol;
            *(bf16x8*)&Bs[lrow * 72 + lcol]     = *(const bf16x8*)gb;
            *(bf16x8*)&Bs[lrow * 72 + lcol + 8] = *(const bf16x8*)(gb + 8);
        }
        __syncthreads();
        for (int ks = 0; ks < 2; ++ks) {
            bf16x8 af[2], bfr[2];
            af[0]  = *(const bf16x8*)&As[(wm * 32 + l16) * 72 + ks * 32 + quad * 8];
            af[1]  = *(const bf16x8*)&As[(wm * 32 + 16 + l16) * 72 + ks * 32 + quad * 8];
            bfr[0] = *(const bf16x8*)&Bs[(wn * 32 + l16) * 72 + ks * 32 + quad * 8];
            bfr[1] = *(const bf16x8*)&Bs[(wn * 32 + 16 + l16) * 72 + ks * 32 + quad * 8];
            for (int mi = 0; mi < 2; ++mi)
                for (int ni = 0; ni < 2; ++ni)
                    acc[mi][ni] = __builtin_amdgcn_mfma_f32_16x16x32_bf16(
                        af[mi], bfr[ni], acc[mi][ni], 0, 0, 0);
        }
    }
}

// ---------------- fused QKV projection (z = 0:Q, 1:K, 2:V) -----------------
struct QKVArgs {
    const bf16_t* Bt[3];
    const float* bias[3];
    void* out[3];
};
__global__ __launch_bounds__(256) void gemm_qkv_kernel(const bf16_t* __restrict__ A, QKVArgs p)
{
    __shared__ __align__(16) bf16_t As[64 * 72];
    __shared__ __align__(16) bf16_t Bs[64 * 72];
    const int z = blockIdx.z;
    const int m0 = blockIdx.y * 64, n0 = blockIdx.x * 64;

    floatx4 acc[2][2] = {};
    gemm_tile64(A, p.Bt[z], As, Bs, m0, n0, acc);

    const int tid  = threadIdx.x;
    const int lane = tid & 63;
    const int quad = lane >> 4, l16 = lane & 15;
    const int wave = tid >> 6;
    const int wm = wave >> 1, wn = wave & 1;
    const float scale = (z == 0) ? QSCALE : 1.0f;
    const float* bias = p.bias[z];

    for (int ni = 0; ni < 2; ++ni) {
        const int col = n0 + wn * 32 + ni * 16 + l16;
        const float bv = bias[col];
        const int h = col >> 6, d = col & 63;
        for (int mi = 0; mi < 2; ++mi) {
            for (int r = 0; r < 4; ++r) {
                const int row = m0 + wm * 32 + mi * 16 + quad * 4 + r;
                const float val = (acc[mi][ni][r] + bv) * scale;
                const int nn = row >> 12, l = row & 4095;
                if (z == 2)
                    ((f16_t*)p.out[2])[(((size_t)nn * HH + h) * DD + d) * LL + l] = (f16_t)val;
                else
                    ((bf16_t*)p.out[z])[(((size_t)nn * HH + h) * LL + l) * DD + d] = (bf16_t)val;
            }
        }
    }
}

// ---------------- output projection (fp32 out) -----------------------------
__global__ __launch_bounds__(256) void gemm_o_kernel(
    const bf16_t* __restrict__ A, const bf16_t* __restrict__ Bt,
    const float* __restrict__ bias, float* __restrict__ Cout)
{
    __shared__ __align__(16) bf16_t As[64 * 72];
    __shared__ __align__(16) bf16_t Bs[64 * 72];
    const int m0 = blockIdx.y * 64, n0 = blockIdx.x * 64;

    floatx4 acc[2][2] = {};
    gemm_tile64(A, Bt, As, Bs, m0, n0, acc);

    const int tid  = threadIdx.x;
    const int lane = tid & 63;
    const int quad = lane >> 4, l16 = lane & 15;
    const int wave = tid >> 6;
    const int wm = wave >> 1, wn = wave & 1;

    for (int ni = 0; ni < 2; ++ni) {
        const int col = n0 + wn * 32 + ni * 16 + l16;
        const float bv = bias[col];
        for (int mi = 0; mi < 2; ++mi)
            for (int r = 0; r < 4; ++r) {
                const int row = m0 + wm * 32 + mi * 16 + quad * 4 + r;
                Cout[(size_t)row * HD_ + col] = acc[mi][ni][r] + bv;
            }
    }
}

// ---------------- flash attention: S^T trick, register-resident P ----------
// S^T = K·Q^T via mfma(A=K, B=Q): C-layout (col=q=l16, row=kv=quad*4+r) is
// exactly the B-operand layout of mfma_f32_16x16x16f16 for O^T = V^T·P^T.
// P never touches LDS. O^T transposed back via LDS once per block.
__global__ __launch_bounds__(256) void attn_kernel(
    const bf16_t* __restrict__ qg, const bf16_t* __restrict__ kg,
    const f16_t* __restrict__ vtg, bf16_t* __restrict__ og)
{
    __shared__ union {
        struct {
            bf16_t Ks[8 * 64 * 8];     // QK^T A-frags (K rows), DMA-staged
            f16_t  Va[16 * 64 * 4];    // PV A-frags (V^T), frag-contiguous
        } s;
        bf16_t OT[128 * 72];           // epilogue transpose buffer
    } u;

    const int tid  = threadIdx.x;
    const int w    = tid >> 6, lane = tid & 63;
    const int quad = lane >> 4, l16 = lane & 15;
    const int qt0  = blockIdx.x * 128;
    const int nh   = blockIdx.y;
    const int nIdx = nh / HH, hIdx = nh % HH;
    const size_t headL = (size_t)nh * LL;

    // resident Q B-frags: B[n=q=l16][k=d=quad*8+j]
    bf16x8 bq[2][2];
    for (int mi = 0; mi < 2; ++mi) {
        const int row = qt0 + w * 32 + mi * 16 + l16;
        const bf16_t* qp = qg + (headL + row) * DD + quad * 8;
        bq[mi][0] = *(const bf16x8*)qp;
        bq[mi][1] = *(const bf16x8*)(qp + 32);
    }

    // K staging via DMA: wave w stages kv-block w
    const bf16_t* kptr = kg + (headL + w * 16 + l16) * DD + quad * 8;
    bf16_t* ldsK0 = &u.s.Ks[(0 * 4 + w) * 512];
    bf16_t* ldsK1 = &u.s.Ks[(1 * 4 + w) * 512];

    // V^T staging: thread owns (d=tid>>2, kv chunk=(tid&3)*16)
    const int dsrc = tid >> 2, cch = tid & 3;
    const f16_t* vptr = vtg + ((size_t)nh * DD + dsrc) * LL + cch * 16;
    f16_t* vdst = &u.s.Va[((cch * 4 + (dsrc >> 4)) * 64 + (dsrc & 15)) * 4];

    floatx4 oacc[4][2] = {};          // [dblk][qblk], O^T frags
    float rowsum[2] = {0.f, 0.f};

    for (int t = 0; t < LL / 64; ++t) {
        f16x8 v0 = *(const f16x8*)vptr;
        f16x8 v1 = *(const f16x8*)(vptr + 8);
        vptr += 64;
        __syncthreads();
        async_load16(kptr,      ldsK0);
        async_load16(kptr + 32, ldsK1);
        kptr += 64 * DD;
        *(f16x4*)(vdst +   0) = __builtin_shufflevector(v0, v0, 0, 1, 2, 3);
        *(f16x4*)(vdst +  64) = __builtin_shufflevector(v0, v0, 4, 5, 6, 7);
        *(f16x4*)(vdst + 128) = __builtin_shufflevector(v1, v1, 0, 1, 2, 3);
        *(f16x4*)(vdst + 192) = __builtin_shufflevector(v1, v1, 4, 5, 6, 7);
        __syncthreads();

        // S^T = K Q^T (Q pre-scaled by QSCALE*log2e at projection)
        floatx4 sacc[4][2] = {};      // [kvblk][qblk]
        for (int ks = 0; ks < 2; ++ks)
            for (int kb = 0; kb < 4; ++kb) {
                bf16x8 ak = *(const bf16x8*)&u.s.Ks[(ks * 4 + kb) * 512 + lane * 8];
                sacc[kb][0] = __builtin_amdgcn_mfma_f32_16x16x32_bf16(ak, bq[0][ks], sacc[kb][0], 0, 0, 0);
                sacc[kb][1] = __builtin_amdgcn_mfma_f32_16x16x32_bf16(ak, bq[1][ks], sacc[kb][1], 0, 0, 0);
            }

        // p = exp2(s); pack to f16 PV B-frags in registers
        f16x4 pf[4][2];
        for (int kb = 0; kb < 4; ++kb)
            for (int mi = 0; mi < 2; ++mi) {
                const float p0 = __builtin_amdgcn_exp2f(sacc[kb][mi][0]);
                const float p1 = __builtin_amdgcn_exp2f(sacc[kb][mi][1]);
                const float p2 = __builtin_amdgcn_exp2f(sacc[kb][mi][2]);
                const float p3 = __builtin_amdgcn_exp2f(sacc[kb][mi][3]);
                rowsum[mi] += (p0 + p1) + (p2 + p3);
                f16x2 lo = pkrtz(p0, p1);
                f16x2 hi = pkrtz(p2, p3);
                pf[kb][mi] = __builtin_shufflevector(lo, hi, 0, 1, 2, 3);
            }

        // O^T += V^T P^T  (16x16x16 f16, K=16 per kv block)
        for (int kb = 0; kb < 4; ++kb)
            for (int db = 0; db < 4; ++db) {
                f16x4 av = *(const f16x4*)&u.s.Va[(kb * 4 + db) * 256 + lane * 4];
                oacc[db][0] = __builtin_amdgcn_mfma_f32_16x16x16f16(av, pf[kb][0], oacc[db][0], 0, 0, 0);
                oacc[db][1] = __builtin_amdgcn_mfma_f32_16x16x16f16(av, pf[kb][1], oacc[db][1], 0, 0, 0);
            }
    }

    // rowsum lives per (q=l16, qblk); reduce across the 4 quads
    float rinv[2];
    for (int mi = 0; mi < 2; ++mi) {
        float s = rowsum[mi];
        s += __shfl_xor(s, 16);
        s += __shfl_xor(s, 32);
        rinv[mi] = __builtin_amdgcn_rcpf(s);
    }

    // transpose O^T -> O via LDS (once per block), coalesced store
    __syncthreads();
    for (int db = 0; db < 4; ++db)
        for (int mi = 0; mi < 2; ++mi) {
            bf16x4 o4;
            for (int r = 0; r < 4; ++r)
                o4[r] = (bf16_t)(oacc[db][mi][r] * rinv[mi]);
            *(bf16x4*)&u.OT[(w * 32 + mi * 16 + l16) * 72 + db * 16 + quad * 4] = o4;
        }
    __syncthreads();

    const int q = tid >> 1, hf = tid & 1;
    const bf16_t* src = &u.OT[q * 72 + hf * 32];
    bf16x8 r0 = *(const bf16x8*)(src + 0);
    bf16x8 r1 = *(const bf16x8*)(src + 8);
    bf16x8 r2 = *(const bf16x8*)(src + 16);
    bf16x8 r3 = *(const bf16x8*)(src + 24);
    bf16_t* dst = og + ((size_t)nIdx * LL + qt0 + q) * HD_ + hIdx * 64 + hf * 32;
    *(bf16x8*)(dst + 0)  = r0;
    *(bf16x8*)(dst + 8)  = r1;
    *(bf16x8*)(dst + 16) = r2;
    *(bf16x8*)(dst + 24) = r3;
}

extern "C" void kernel_launch(void* const* d_in, const int* in_sizes, int n_in,
                              void* d_out, int out_size, void* d_ws, size_t ws_size,
                              hipStream_t stream) {
    const float* x  = (const float*)d_in[0];
    const float* Wq = (const float*)d_in[1];
    const float* bq = (const float*)d_in[2];
    const float* Wk = (const float*)d_in[3];
    const float* bk = (const float*)d_in[4];
    const float* Wv = (const float*)d_in[5];
    const float* bv = (const float*)d_in[6];
    const float* Wo = (const float*)d_in[7];
    const float* bo = (const float*)d_in[8];

    char* ws = (char*)d_ws;
    const size_t xbytes = (size_t)M_TOT * HD_ * 2;
    const size_t wbytes = (size_t)HD_ * HD_ * 2;

    bf16_t* xb  = (bf16_t*)ws; ws += xbytes;
    bf16_t* wqt = (bf16_t*)ws; ws += wbytes;
    bf16_t* wkt = (bf16_t*)ws; ws += wbytes;
    bf16_t* wvt = (bf16_t*)ws; ws += wbytes;
    bf16_t* wot = (bf16_t*)ws; ws += wbytes;
    bf16_t* qb  = (bf16_t*)ws; ws += xbytes;
    bf16_t* kb  = (bf16_t*)ws; ws += xbytes;
    f16_t*  vtb = (f16_t*)ws;  ws += xbytes;
    bf16_t* ob  = (bf16_t*)ws; ws += xbytes;

    cvt_kernel<<<(M_TOT * HD_ / 4 + 255) / 256, 256, 0, stream>>>(x, xb, M_TOT * HD_ / 4);

    WtArgs wa;
    wa.W[0] = Wq; wa.W[1] = Wk; wa.W[2] = Wv; wa.W[3] = Wo;
    wa.Wt[0] = wqt; wa.Wt[1] = wkt; wa.Wt[2] = wvt; wa.Wt[3] = wot;
    cvt_wt_kernel<<<dim3(HD_ * HD_ / 256, 1, 4), 256, 0, stream>>>(wa);

    QKVArgs qa;
    qa.Bt[0] = wqt; qa.Bt[1] = wkt; qa.Bt[2] = wvt;
    qa.bias[0] = bq; qa.bias[1] = bk; qa.bias[2] = bv;
    qa.out[0] = qb; qa.out[1] = kb; qa.out[2] = vtb;
    gemm_qkv_kernel<<<dim3(HD_ / 64, M_TOT / 64, 3), 256, 0, stream>>>(xb, qa);

    attn_kernel<<<dim3(LL / 128, NN * HH), 256, 0, stream>>>(qb, kb, vtb, ob);

    gemm_o_kernel<<<dim3(HD_ / 64, M_TOT / 64), 256, 0, stream>>>(ob, wot, bo, (float*)d_out);
}

// Round 5
// 353.260 us; speedup vs baseline: 1.0373x; 1.0373x over previous
//
#include <hip/hip_runtime.h>

#define NN 2
#define LL 4096
#define HH 12
#define DD 64
#define HD_ 768
#define M_TOT (NN * LL)   // 8192
#define KVSTRIDE 262144   // elems per (n,h) in pre-permuted K'/V' layouts

typedef __bf16 bf16_t;
typedef _Float16 f16_t;
typedef __bf16 bf16x8 __attribute__((ext_vector_type(8)));
typedef __bf16 bf16x4 __attribute__((ext_vector_type(4)));
typedef _Float16 f16x2 __attribute__((ext_vector_type(2)));
typedef _Float16 f16x4 __attribute__((ext_vector_type(4)));
typedef _Float16 f16x8 __attribute__((ext_vector_type(8)));
typedef float floatx4 __attribute__((ext_vector_type(4)));
typedef float floatx16 __attribute__((ext_vector_type(16)));

// softmax prescale folded into Q at the QKV GEMM: 1/sqrt(64) * log2(e)
#define QSCALE 0.1803368801111f

__device__ __forceinline__ void async_load16(const void* g, void* l) {
    __builtin_amdgcn_global_load_lds(
        (const __attribute__((address_space(1))) unsigned int*)(g),
        (__attribute__((address_space(3))) unsigned int*)(l),
        16, 0, 0);
}

__device__ __forceinline__ f16x2 pkrtz(float a, float b) {
    return __builtin_bit_cast(f16x2, __builtin_amdgcn_cvt_pkrtz(a, b));
}

__device__ __forceinline__ f16x4 shflx32(f16x4 v) {
    int2 iv = __builtin_bit_cast(int2, v);
    iv.x = __shfl_xor(iv.x, 32);
    iv.y = __shfl_xor(iv.y, 32);
    return __builtin_bit_cast(f16x4, iv);
}

// ---------------- fp32 -> bf16 convert (x) ---------------------------------
__global__ void cvt_kernel(const float* __restrict__ src, bf16_t* __restrict__ dst, int n4) {
    int i = blockIdx.x * blockDim.x + threadIdx.x;
    if (i < n4) {
        const float4 v = ((const float4*)src)[i];
        bf16_t* d = dst + (size_t)i * 4;
        d[0] = (bf16_t)v.x; d[1] = (bf16_t)v.y; d[2] = (bf16_t)v.z; d[3] = (bf16_t)v.w;
    }
}

// ------------- fp32 W (K x N) -> bf16 W^T (N x K), 4 weights fused ---------
struct WtArgs { const float* W[4]; bf16_t* Wt[4]; };
__global__ void cvt_wt_kernel(WtArgs a) {
    const int z = blockIdx.z;
    int id = blockIdx.x * 256 + threadIdx.x;
    int k = id / HD_;
    int n = id % HD_;
    a.Wt[z][(size_t)n * HD_ + k] = (bf16_t)a.W[z][id];
}

// ---------------- shared 64x64 GEMM tile core ------------------------------
__device__ __forceinline__ void gemm_tile64(
    const bf16_t* __restrict__ A, const bf16_t* __restrict__ Bt,
    bf16_t* As, bf16_t* Bs, int m0, int n0, floatx4 (&acc)[2][2])
{
    const int tid  = threadIdx.x;
    const int lane = tid & 63;
    const int quad = lane >> 4, l16 = lane & 15;
    const int wave = tid >> 6;
    const int wm = wave >> 1, wn = wave & 1;
    const int lrow = tid >> 2;
    const int lcol = (tid & 3) * 16;

    for (int kt = 0; kt < HD_; kt += 64) {
        __syncthreads();
        {
            const bf16_t* ga = A + (size_t)(m0 + lrow) * HD_ + kt + lcol;
            *(bf16x8*)&As[lrow * 72 + lcol]     = *(const bf16x8*)ga;
            *(bf16x8*)&As[lrow * 72 + lcol + 8] = *(const bf16x8*)(ga + 8);
            const bf16_t* gb = Bt + (size_t)(n0 + lrow) * HD_ + kt + lcol;
            *(bf16x8*)&Bs[lrow * 72 + lcol]     = *(const bf16x8*)gb;
            *(bf16x8*)&Bs[lrow * 72 + lcol + 8] = *(const bf16x8*)(gb + 8);
        }
        __syncthreads();
        for (int ks = 0; ks < 2; ++ks) {
            bf16x8 af[2], bfr[2];
            af[0]  = *(const bf16x8*)&As[(wm * 32 + l16) * 72 + ks * 32 + quad * 8];
            af[1]  = *(const bf16x8*)&As[(wm * 32 + 16 + l16) * 72 + ks * 32 + quad * 8];
            bfr[0] = *(const bf16x8*)&Bs[(wn * 32 + l16) * 72 + ks * 32 + quad * 8];
            bfr[1] = *(const bf16x8*)&Bs[(wn * 32 + 16 + l16) * 72 + ks * 32 + quad * 8];
            for (int mi = 0; mi < 2; ++mi)
                for (int ni = 0; ni < 2; ++ni)
                    acc[mi][ni] = __builtin_amdgcn_mfma_f32_16x16x32_bf16(
                        af[mi], bfr[ni], acc[mi][ni], 0, 0, 0);
        }
    }
}

// ---------------- fused QKV projection (z = 0:Q, 1:K, 2:V) -----------------
// Q -> (n,h,l,d) bf16 (pre-scaled).
// K -> K' fragment layout: nh | kvb=l>>5 | s=d>>4 | lane=(l&31)+32*((d>>3)&1) | j=d&7
// V -> V' fragment layout: nh | t=l>>6 | dblk=d>>5 | kstep=(l>>4)&3 |
//                          lane=(d&31)+32*((l>>3)&1) | j=l&7   (f16)
struct QKVArgs {
    const bf16_t* Bt[3];
    const float* bias[3];
    void* out[3];
};
__global__ __launch_bounds__(256) void gemm_qkv_kernel(const bf16_t* __restrict__ A, QKVArgs p)
{
    __shared__ __align__(16) bf16_t As[64 * 72];
    __shared__ __align__(16) bf16_t Bs[64 * 72];
    const int z = blockIdx.z;
    const int m0 = blockIdx.y * 64, n0 = blockIdx.x * 64;

    floatx4 acc[2][2] = {};
    gemm_tile64(A, p.Bt[z], As, Bs, m0, n0, acc);

    const int tid  = threadIdx.x;
    const int lane = tid & 63;
    const int quad = lane >> 4, l16 = lane & 15;
    const int wave = tid >> 6;
    const int wm = wave >> 1, wn = wave & 1;
    const float scale = (z == 0) ? QSCALE : 1.0f;
    const float* bias = p.bias[z];

    for (int ni = 0; ni < 2; ++ni) {
        const int col = n0 + wn * 32 + ni * 16 + l16;
        const float bv = bias[col];
        const int h = col >> 6, d = col & 63;
        for (int mi = 0; mi < 2; ++mi) {
            for (int r = 0; r < 4; ++r) {
                const int row = m0 + wm * 32 + mi * 16 + quad * 4 + r;
                const float val = (acc[mi][ni][r] + bv) * scale;
                const int nn = row >> 12, l = row & 4095;
                const size_t nhb = (size_t)(nn * HH + h) * KVSTRIDE;
                if (z == 0) {
                    ((bf16_t*)p.out[0])[(((size_t)nn * HH + h) * LL + l) * DD + d] = (bf16_t)val;
                } else if (z == 1) {
                    size_t idx = nhb + (size_t)((l >> 5) * 4 + (d >> 4)) * 512
                               + ((l & 31) + 32 * ((d >> 3) & 1)) * 8 + (d & 7);
                    ((bf16_t*)p.out[1])[idx] = (bf16_t)val;
                } else {
                    size_t idx = nhb + (size_t)(((l >> 6) * 2 + (d >> 5)) * 4 + ((l >> 4) & 3)) * 512
                               + ((d & 31) + 32 * ((l >> 3) & 1)) * 8 + (l & 7);
                    ((f16_t*)p.out[2])[idx] = (f16_t)val;
                }
            }
        }
    }
}

// ---------------- output projection (fp32 out) -----------------------------
__global__ __launch_bounds__(256) void gemm_o_kernel(
    const bf16_t* __restrict__ A, const bf16_t* __restrict__ Bt,
    const float* __restrict__ bias, float* __restrict__ Cout)
{
    __shared__ __align__(16) bf16_t As[64 * 72];
    __shared__ __align__(16) bf16_t Bs[64 * 72];
    const int m0 = blockIdx.y * 64, n0 = blockIdx.x * 64;

    floatx4 acc[2][2] = {};
    gemm_tile64(A, Bt, As, Bs, m0, n0, acc);

    const int tid  = threadIdx.x;
    const int lane = tid & 63;
    const int quad = lane >> 4, l16 = lane & 15;
    const int wave = tid >> 6;
    const int wm = wave >> 1, wn = wave & 1;

    for (int ni = 0; ni < 2; ++ni) {
        const int col = n0 + wn * 32 + ni * 16 + l16;
        const float bv = bias[col];
        for (int mi = 0; mi < 2; ++mi)
            for (int r = 0; r < 4; ++r) {
                const int row = m0 + wm * 32 + mi * 16 + quad * 4 + r;
                Cout[(size_t)row * HD_ + col] = acc[mi][ni][r] + bv;
            }
    }
}

// ---------------- flash attention, 32x32 fragments -------------------------
// S^T = K·Q^T via mfma_32x32x16_bf16 (A=K' frags, B=Q). C-layout:
// col=q=lane&31, row=kv=(reg&3)+8*(reg>>2)+4*hi. B-frag for PV K=16 needs
// k=hi*8+j per lane -> built with 2 shfl_xor(32) + 4 cndmask per 8 regs.
// O^T += V^T·P^T via mfma_32x32x16_f16 (A=V' frags). All LDS reads are
// base+lane*16 (conflict-free); staging is contiguous 1KB DMA.
__global__ __launch_bounds__(256) void attn_kernel(
    const bf16_t* __restrict__ qg, const bf16_t* __restrict__ kf,
    const f16_t* __restrict__ vf, bf16_t* __restrict__ og)
{
    __shared__ union {
        struct {
            bf16_t Ks[8 * 512];   // 8 K frags (kvb*4+s), 1KB each
            f16_t  Vs[8 * 512];   // 8 V frags (dblk*4+kstep), 1KB each
        } s;
        bf16_t OT[128 * 72];      // epilogue transpose buffer
    } u;

    const int tid = threadIdx.x;
    const int w = tid >> 6, lane = tid & 63;
    const int l32 = lane & 31, hi = lane >> 5;
    const int qt0 = blockIdx.x * 128;
    const int nh = blockIdx.y;
    const int nIdx = nh / HH, hIdx = nh % HH;

    // Q B-frags: lane (q=l32, hi) holds Q[q0+l32][s*16 + hi*8 + j]
    bf16x8 qfrag[4];
    {
        const bf16_t* qp = qg + ((size_t)nh * LL + qt0 + w * 32 + l32) * DD + hi * 8;
        for (int s = 0; s < 4; ++s) qfrag[s] = *(const bf16x8*)(qp + s * 16);
    }

    // DMA: wave w stages K chunks {2w,2w+1} and V chunks {2w,2w+1}
    const bf16_t* ksrc = kf + (size_t)nh * KVSTRIDE + (2 * w) * 512 + lane * 8;
    const f16_t*  vsrc = vf + (size_t)nh * KVSTRIDE + (2 * w) * 512 + lane * 8;
    bf16_t* kdst0 = &u.s.Ks[(2 * w) * 512 + lane * 8];
    bf16_t* kdst1 = &u.s.Ks[(2 * w + 1) * 512 + lane * 8];
    f16_t*  vdst0 = &u.s.Vs[(2 * w) * 512 + lane * 8];
    f16_t*  vdst1 = &u.s.Vs[(2 * w + 1) * 512 + lane * 8];

    floatx16 oacc[2] = {};
    float rs = 0.f;

    for (int t = 0; t < LL / 64; ++t) {
        __syncthreads();
        async_load16(ksrc, kdst0);
        async_load16(ksrc + 512, kdst1);
        async_load16(vsrc, vdst0);
        async_load16(vsrc + 512, vdst1);
        ksrc += 4096; vsrc += 4096;
        __syncthreads();

        for (int kvb = 0; kvb < 2; ++kvb) {
            floatx16 sacc = {};
            for (int s = 0; s < 4; ++s) {
                bf16x8 ak = *(const bf16x8*)&u.s.Ks[(kvb * 4 + s) * 512 + lane * 8];
                sacc = __builtin_amdgcn_mfma_f32_32x32x16_bf16(ak, qfrag[s], sacc, 0, 0, 0);
            }
            for (int sub = 0; sub < 2; ++sub) {
                float p[8];
                for (int i = 0; i < 8; ++i) {
                    p[i] = __builtin_amdgcn_exp2f(sacc[sub * 8 + i]);
                    rs += p[i];
                }
                f16x2 l01 = pkrtz(p[0], p[1]), l23 = pkrtz(p[2], p[3]);
                f16x2 h45 = pkrtz(p[4], p[5]), h67 = pkrtz(p[6], p[7]);
                f16x4 Lo = __builtin_shufflevector(l01, l23, 0, 1, 2, 3);
                f16x4 Hh = __builtin_shufflevector(h45, h67, 0, 1, 2, 3);
                f16x4 swL = shflx32(Lo);
                f16x4 swH = shflx32(Hh);
                f16x4 a03 = hi ? swH : Lo;    // j = 0..3
                f16x4 a47 = hi ? Hh : swL;    // j = 4..7
                f16x8 pf = __builtin_shufflevector(a03, a47, 0, 1, 2, 3, 4, 5, 6, 7);
                const int kstep = kvb * 2 + sub;
                for (int db = 0; db < 2; ++db) {
                    f16x8 av = *(const f16x8*)&u.s.Vs[(db * 4 + kstep) * 512 + lane * 8];
                    oacc[db] = __builtin_amdgcn_mfma_f32_32x32x16_f16(av, pf, oacc[db], 0, 0, 0);
                }
            }
        }
    }

    // full row sum per q: add the partner half-wave's partial
    rs += __shfl_xor(rs, 32);
    const float rinv = __builtin_amdgcn_rcpf(rs);

    // O^T -> O via LDS transpose, then coalesced store
    __syncthreads();
    for (int db = 0; db < 2; ++db)
        for (int g = 0; g < 4; ++g) {
            bf16x4 o4;
            for (int r = 0; r < 4; ++r)
                o4[r] = (bf16_t)(oacc[db][g * 4 + r] * rinv);
            // d = r + 8g + 4hi + 32db
            *(bf16x4*)&u.OT[(w * 32 + l32) * 72 + db * 32 + hi * 4 + g * 8] = o4;
        }
    __syncthreads();

    const int q = tid >> 1, hf = tid & 1;
    const bf16_t* src = &u.OT[q * 72 + hf * 32];
    bf16x8 r0 = *(const bf16x8*)(src + 0);
    bf16x8 r1 = *(const bf16x8*)(src + 8);
    bf16x8 r2 = *(const bf16x8*)(src + 16);
    bf16x8 r3 = *(const bf16x8*)(src + 24);
    bf16_t* dst = og + ((size_t)nIdx * LL + qt0 + q) * HD_ + hIdx * 64 + hf * 32;
    *(bf16x8*)(dst + 0)  = r0;
    *(bf16x8*)(dst + 8)  = r1;
    *(bf16x8*)(dst + 16) = r2;
    *(bf16x8*)(dst + 24) = r3;
}

extern "C" void kernel_launch(void* const* d_in, const int* in_sizes, int n_in,
                              void* d_out, int out_size, void* d_ws, size_t ws_size,
                              hipStream_t stream) {
    const float* x  = (const float*)d_in[0];
    const float* Wq = (const float*)d_in[1];
    const float* bq = (const float*)d_in[2];
    const float* Wk = (const float*)d_in[3];
    const float* bk = (const float*)d_in[4];
    const float* Wv = (const float*)d_in[5];
    const float* bv = (const float*)d_in[6];
    const float* Wo = (const float*)d_in[7];
    const float* bo = (const float*)d_in[8];

    char* ws = (char*)d_ws;
    const size_t xbytes = (size_t)M_TOT * HD_ * 2;
    const size_t wbytes = (size_t)HD_ * HD_ * 2;

    bf16_t* xb  = (bf16_t*)ws; ws += xbytes;
    bf16_t* wqt = (bf16_t*)ws; ws += wbytes;
    bf16_t* wkt = (bf16_t*)ws; ws += wbytes;
    bf16_t* wvt = (bf16_t*)ws; ws += wbytes;
    bf16_t* wot = (bf16_t*)ws; ws += wbytes;
    bf16_t* qb  = (bf16_t*)ws; ws += xbytes;
    bf16_t* kfb = (bf16_t*)ws; ws += xbytes;
    f16_t*  vfb = (f16_t*)ws;  ws += xbytes;
    bf16_t* ob  = (bf16_t*)ws; ws += xbytes;

    cvt_kernel<<<(M_TOT * HD_ / 4 + 255) / 256, 256, 0, stream>>>(x, xb, M_TOT * HD_ / 4);

    WtArgs wa;
    wa.W[0] = Wq; wa.W[1] = Wk; wa.W[2] = Wv; wa.W[3] = Wo;
    wa.Wt[0] = wqt; wa.Wt[1] = wkt; wa.Wt[2] = wvt; wa.Wt[3] = wot;
    cvt_wt_kernel<<<dim3(HD_ * HD_ / 256, 1, 4), 256, 0, stream>>>(wa);

    QKVArgs qa;
    qa.Bt[0] = wqt; qa.Bt[1] = wkt; qa.Bt[2] = wvt;
    qa.bias[0] = bq; qa.bias[1] = bk; qa.bias[2] = bv;
    qa.out[0] = qb; qa.out[1] = kfb; qa.out[2] = vfb;
    gemm_qkv_kernel<<<dim3(HD_ / 64, M_TOT / 64, 3), 256, 0, stream>>>(xb, qa);

    attn_kernel<<<dim3(LL / 128, NN * HH), 256, 0, stream>>>(qb, kfb, vfb, ob);

    gemm_o_kernel<<<dim3(HD_ / 64, M_TOT / 64), 256, 0, stream>>>(ob, wot, bo, (float*)d_out);
}

// Round 6
// 339.125 us; speedup vs baseline: 1.0805x; 1.0417x over previous
//
#include <hip/hip_runtime.h>

#define NN 2
#define LL 4096
#define HH 12
#define DD 64
#define HD_ 768
#define M_TOT (NN * LL)   // 8192
#define KVSTRIDE 262144   // elems per (n,h) in pre-permuted K'/V' layouts

typedef __bf16 bf16_t;
typedef _Float16 f16_t;
typedef __bf16 bf16x8 __attribute__((ext_vector_type(8)));
typedef __bf16 bf16x4 __attribute__((ext_vector_type(4)));
typedef _Float16 f16x2 __attribute__((ext_vector_type(2)));
typedef _Float16 f16x4 __attribute__((ext_vector_type(4)));
typedef _Float16 f16x8 __attribute__((ext_vector_type(8)));
typedef float floatx4 __attribute__((ext_vector_type(4)));
typedef float floatx16 __attribute__((ext_vector_type(16)));

// softmax prescale folded into Q at the QKV GEMM: 1/sqrt(64) * log2(e)
#define QSCALE 0.1803368801111f

__device__ __forceinline__ void async_load16(const void* g, void* l) {
    __builtin_amdgcn_global_load_lds(
        (const __attribute__((address_space(1))) unsigned int*)(g),
        (__attribute__((address_space(3))) unsigned int*)(l),
        16, 0, 0);
}

__device__ __forceinline__ f16x2 pkrtz(float a, float b) {
    return __builtin_bit_cast(f16x2, __builtin_amdgcn_cvt_pkrtz(a, b));
}

__device__ __forceinline__ f16x4 shflx32(f16x4 v) {
    int2 iv = __builtin_bit_cast(int2, v);
    iv.x = __shfl_xor(iv.x, 32);
    iv.y = __shfl_xor(iv.y, 32);
    return __builtin_bit_cast(f16x4, iv);
}

// ---------------- fp32 -> bf16 convert (x) ---------------------------------
__global__ void cvt_kernel(const float* __restrict__ src, bf16_t* __restrict__ dst, int n4) {
    int i = blockIdx.x * blockDim.x + threadIdx.x;
    if (i < n4) {
        const float4 v = ((const float4*)src)[i];
        bf16_t* d = dst + (size_t)i * 4;
        d[0] = (bf16_t)v.x; d[1] = (bf16_t)v.y; d[2] = (bf16_t)v.z; d[3] = (bf16_t)v.w;
    }
}

// ------------- fp32 W (K x N) -> bf16 W^T (N x K), 4 weights fused ---------
struct WtArgs { const float* W[4]; bf16_t* Wt[4]; };
__global__ void cvt_wt_kernel(WtArgs a) {
    const int z = blockIdx.z;
    int id = blockIdx.x * 256 + threadIdx.x;
    int k = id / HD_;
    int n = id % HD_;
    a.Wt[z][(size_t)n * HD_ + k] = (bf16_t)a.W[z][id];
}

// ---------------- m97-style 128x128 GEMM tile core -------------------------
// A (Mx768) row-major bf16, Bt (Nx768) row-major bf16 (i.e. W^T).
// 256 threads = 4 waves in 2x2; each wave computes 64x64 via 4x4 16x16x32.
// Staging: pure global_load_lds width-16 DMA into unpadded [128][64] tiles.
__device__ __forceinline__ void gemm_tile128(
    const bf16_t* __restrict__ A, const bf16_t* __restrict__ Bt,
    bf16_t* As, bf16_t* Bs, int m0, int n0, floatx4 (&acc)[4][4])
{
    const int tid  = threadIdx.x;
    const int w    = tid >> 6, lane = tid & 63;
    const int quad = lane >> 4, l16 = lane & 15;
    const int wm = w >> 1, wn = w & 1;
    const int rsub = lane >> 3;          // 0..7 rows within an 8-row group
    const int csub = (lane & 7) * 8;     // col elems 0..56

    const bf16_t* aBase = A + (size_t)(m0 + w * 32 + rsub) * HD_ + csub;
    const bf16_t* bBase = Bt + (size_t)(n0 + w * 32 + rsub) * HD_ + csub;

    for (int kt = 0; kt < HD_; kt += 64) {
        __syncthreads();
        for (int i = 0; i < 4; ++i) {
            const int ar = w * 32 + i * 8;
            async_load16(aBase + (size_t)i * 8 * HD_ + kt, As + ar * 64 + lane * 8);
            async_load16(bBase + (size_t)i * 8 * HD_ + kt, Bs + ar * 64 + lane * 8);
        }
        __syncthreads();
        for (int ks = 0; ks < 2; ++ks) {
            bf16x8 af[4], bf[4];
            for (int mi = 0; mi < 4; ++mi)
                af[mi] = *(const bf16x8*)&As[(wm * 64 + mi * 16 + l16) * 64 + ks * 32 + quad * 8];
            for (int ni = 0; ni < 4; ++ni)
                bf[ni] = *(const bf16x8*)&Bs[(wn * 64 + ni * 16 + l16) * 64 + ks * 32 + quad * 8];
            for (int mi = 0; mi < 4; ++mi)
                for (int ni = 0; ni < 4; ++ni)
                    acc[mi][ni] = __builtin_amdgcn_mfma_f32_16x16x32_bf16(
                        af[mi], bf[ni], acc[mi][ni], 0, 0, 0);
        }
    }
}

// ---------------- fused QKV projection (z = 0:Q, 1:K, 2:V) -----------------
// Q -> (n,h,l,d) bf16 (pre-scaled).
// K -> K' fragment layout: nh | kvb=l>>5 | s=d>>4 | lane=(l&31)+32*((d>>3)&1) | j=d&7
// V -> V' fragment layout: nh | t=l>>6 | dblk=d>>5 | kstep=(l>>4)&3 |
//                          lane=(d&31)+32*((l>>3)&1) | j=l&7   (f16)
struct QKVArgs {
    const bf16_t* Bt[3];
    const float* bias[3];
    void* out[3];
};
__global__ __launch_bounds__(256) void gemm_qkv_kernel(const bf16_t* __restrict__ A, QKVArgs p)
{
    __shared__ __align__(16) bf16_t As[128 * 64];
    __shared__ __align__(16) bf16_t Bs[128 * 64];
    const int z = blockIdx.z;
    const int m0 = blockIdx.y * 128, n0 = blockIdx.x * 128;

    floatx4 acc[4][4] = {};
    gemm_tile128(A, p.Bt[z], As, Bs, m0, n0, acc);

    const int tid  = threadIdx.x;
    const int lane = tid & 63;
    const int quad = lane >> 4, l16 = lane & 15;
    const int w    = tid >> 6;
    const int wm = w >> 1, wn = w & 1;
    const float scale = (z == 0) ? QSCALE : 1.0f;
    const float* bias = p.bias[z];

    for (int ni = 0; ni < 4; ++ni) {
        const int col = n0 + wn * 64 + ni * 16 + l16;
        const float bv = bias[col];
        const int h = col >> 6, d = col & 63;
        for (int mi = 0; mi < 4; ++mi) {
            for (int r = 0; r < 4; ++r) {
                const int row = m0 + wm * 64 + mi * 16 + quad * 4 + r;
                const float val = (acc[mi][ni][r] + bv) * scale;
                const int nn = row >> 12, l = row & 4095;
                const size_t nhb = (size_t)(nn * HH + h) * KVSTRIDE;
                if (z == 0) {
                    ((bf16_t*)p.out[0])[(((size_t)nn * HH + h) * LL + l) * DD + d] = (bf16_t)val;
                } else if (z == 1) {
                    size_t idx = nhb + (size_t)((l >> 5) * 4 + (d >> 4)) * 512
                               + ((l & 31) + 32 * ((d >> 3) & 1)) * 8 + (d & 7);
                    ((bf16_t*)p.out[1])[idx] = (bf16_t)val;
                } else {
                    size_t idx = nhb + (size_t)(((l >> 6) * 2 + (d >> 5)) * 4 + ((l >> 4) & 3)) * 512
                               + ((d & 31) + 32 * ((l >> 3) & 1)) * 8 + (l & 7);
                    ((f16_t*)p.out[2])[idx] = (f16_t)val;
                }
            }
        }
    }
}

// ---------------- output projection (fp32 out) -----------------------------
__global__ __launch_bounds__(256) void gemm_o_kernel(
    const bf16_t* __restrict__ A, const bf16_t* __restrict__ Bt,
    const float* __restrict__ bias, float* __restrict__ Cout)
{
    __shared__ __align__(16) bf16_t As[128 * 64];
    __shared__ __align__(16) bf16_t Bs[128 * 64];
    const int m0 = blockIdx.y * 128, n0 = blockIdx.x * 128;

    floatx4 acc[4][4] = {};
    gemm_tile128(A, Bt, As, Bs, m0, n0, acc);

    const int tid  = threadIdx.x;
    const int lane = tid & 63;
    const int quad = lane >> 4, l16 = lane & 15;
    const int w    = tid >> 6;
    const int wm = w >> 1, wn = w & 1;

    for (int ni = 0; ni < 4; ++ni) {
        const int col = n0 + wn * 64 + ni * 16 + l16;
        const float bv = bias[col];
        for (int mi = 0; mi < 4; ++mi)
            for (int r = 0; r < 4; ++r) {
                const int row = m0 + wm * 64 + mi * 16 + quad * 4 + r;
                Cout[(size_t)row * HD_ + col] = acc[mi][ni][r] + bv;
            }
    }
}

// ---------------- flash attention, 32x32 fragments (unchanged) -------------
__global__ __launch_bounds__(256) void attn_kernel(
    const bf16_t* __restrict__ qg, const bf16_t* __restrict__ kf,
    const f16_t* __restrict__ vf, bf16_t* __restrict__ og)
{
    __shared__ union {
        struct {
            bf16_t Ks[8 * 512];   // 8 K frags (kvb*4+s), 1KB each
            f16_t  Vs[8 * 512];   // 8 V frags (dblk*4+kstep), 1KB each
        } s;
        bf16_t OT[128 * 72];      // epilogue transpose buffer
    } u;

    const int tid = threadIdx.x;
    const int w = tid >> 6, lane = tid & 63;
    const int l32 = lane & 31, hi = lane >> 5;
    const int qt0 = blockIdx.x * 128;
    const int nh = blockIdx.y;
    const int nIdx = nh / HH, hIdx = nh % HH;

    // Q B-frags: lane (q=l32, hi) holds Q[q0+l32][s*16 + hi*8 + j]
    bf16x8 qfrag[4];
    {
        const bf16_t* qp = qg + ((size_t)nh * LL + qt0 + w * 32 + l32) * DD + hi * 8;
        for (int s = 0; s < 4; ++s) qfrag[s] = *(const bf16x8*)(qp + s * 16);
    }

    // DMA: wave w stages K chunks {2w,2w+1} and V chunks {2w,2w+1}
    const bf16_t* ksrc = kf + (size_t)nh * KVSTRIDE + (2 * w) * 512 + lane * 8;
    const f16_t*  vsrc = vf + (size_t)nh * KVSTRIDE + (2 * w) * 512 + lane * 8;
    bf16_t* kdst0 = &u.s.Ks[(2 * w) * 512 + lane * 8];
    bf16_t* kdst1 = &u.s.Ks[(2 * w + 1) * 512 + lane * 8];
    f16_t*  vdst0 = &u.s.Vs[(2 * w) * 512 + lane * 8];
    f16_t*  vdst1 = &u.s.Vs[(2 * w + 1) * 512 + lane * 8];

    floatx16 oacc[2] = {};
    float rs = 0.f;

    for (int t = 0; t < LL / 64; ++t) {
        __syncthreads();
        async_load16(ksrc, kdst0);
        async_load16(ksrc + 512, kdst1);
        async_load16(vsrc, vdst0);
        async_load16(vsrc + 512, vdst1);
        ksrc += 4096; vsrc += 4096;
        __syncthreads();

        for (int kvb = 0; kvb < 2; ++kvb) {
            floatx16 sacc = {};
            for (int s = 0; s < 4; ++s) {
                bf16x8 ak = *(const bf16x8*)&u.s.Ks[(kvb * 4 + s) * 512 + lane * 8];
                sacc = __builtin_amdgcn_mfma_f32_32x32x16_bf16(ak, qfrag[s], sacc, 0, 0, 0);
            }
            for (int sub = 0; sub < 2; ++sub) {
                float p[8];
                for (int i = 0; i < 8; ++i) {
                    p[i] = __builtin_amdgcn_exp2f(sacc[sub * 8 + i]);
                    rs += p[i];
                }
                f16x2 l01 = pkrtz(p[0], p[1]), l23 = pkrtz(p[2], p[3]);
                f16x2 h45 = pkrtz(p[4], p[5]), h67 = pkrtz(p[6], p[7]);
                f16x4 Lo = __builtin_shufflevector(l01, l23, 0, 1, 2, 3);
                f16x4 Hh = __builtin_shufflevector(h45, h67, 0, 1, 2, 3);
                f16x4 swL = shflx32(Lo);
                f16x4 swH = shflx32(Hh);
                f16x4 a03 = hi ? swH : Lo;    // j = 0..3
                f16x4 a47 = hi ? Hh : swL;    // j = 4..7
                f16x8 pf = __builtin_shufflevector(a03, a47, 0, 1, 2, 3, 4, 5, 6, 7);
                const int kstep = kvb * 2 + sub;
                for (int db = 0; db < 2; ++db) {
                    f16x8 av = *(const f16x8*)&u.s.Vs[(db * 4 + kstep) * 512 + lane * 8];
                    oacc[db] = __builtin_amdgcn_mfma_f32_32x32x16_f16(av, pf, oacc[db], 0, 0, 0);
                }
            }
        }
    }

    // full row sum per q: add the partner half-wave's partial
    rs += __shfl_xor(rs, 32);
    const float rinv = __builtin_amdgcn_rcpf(rs);

    // O^T -> O via LDS transpose, then coalesced store
    __syncthreads();
    for (int db = 0; db < 2; ++db)
        for (int g = 0; g < 4; ++g) {
            bf16x4 o4;
            for (int r = 0; r < 4; ++r)
                o4[r] = (bf16_t)(oacc[db][g * 4 + r] * rinv);
            // d = r + 8g + 4hi + 32db
            *(bf16x4*)&u.OT[(w * 32 + l32) * 72 + db * 32 + hi * 4 + g * 8] = o4;
        }
    __syncthreads();

    const int q = tid >> 1, hf = tid & 1;
    const bf16_t* src = &u.OT[q * 72 + hf * 32];
    bf16x8 r0 = *(const bf16x8*)(src + 0);
    bf16x8 r1 = *(const bf16x8*)(src + 8);
    bf16x8 r2 = *(const bf16x8*)(src + 16);
    bf16x8 r3 = *(const bf16x8*)(src + 24);
    bf16_t* dst = og + ((size_t)nIdx * LL + qt0 + q) * HD_ + hIdx * 64 + hf * 32;
    *(bf16x8*)(dst + 0)  = r0;
    *(bf16x8*)(dst + 8)  = r1;
    *(bf16x8*)(dst + 16) = r2;
    *(bf16x8*)(dst + 24) = r3;
}

extern "C" void kernel_launch(void* const* d_in, const int* in_sizes, int n_in,
                              void* d_out, int out_size, void* d_ws, size_t ws_size,
                              hipStream_t stream) {
    const float* x  = (const float*)d_in[0];
    const float* Wq = (const float*)d_in[1];
    const float* bq = (const float*)d_in[2];
    const float* Wk = (const float*)d_in[3];
    const float* bk = (const float*)d_in[4];
    const float* Wv = (const float*)d_in[5];
    const float* bv = (const float*)d_in[6];
    const float* Wo = (const float*)d_in[7];
    const float* bo = (const float*)d_in[8];

    char* ws = (char*)d_ws;
    const size_t xbytes = (size_t)M_TOT * HD_ * 2;
    const size_t wbytes = (size_t)HD_ * HD_ * 2;

    bf16_t* xb  = (bf16_t*)ws; ws += xbytes;
    bf16_t* wqt = (bf16_t*)ws; ws += wbytes;
    bf16_t* wkt = (bf16_t*)ws; ws += wbytes;
    bf16_t* wvt = (bf16_t*)ws; ws += wbytes;
    bf16_t* wot = (bf16_t*)ws; ws += wbytes;
    bf16_t* qb  = (bf16_t*)ws; ws += xbytes;
    bf16_t* kfb = (bf16_t*)ws; ws += xbytes;
    f16_t*  vfb = (f16_t*)ws;  ws += xbytes;
    bf16_t* ob  = (bf16_t*)ws; ws += xbytes;

    cvt_kernel<<<(M_TOT * HD_ / 4 + 255) / 256, 256, 0, stream>>>(x, xb, M_TOT * HD_ / 4);

    WtArgs wa;
    wa.W[0] = Wq; wa.W[1] = Wk; wa.W[2] = Wv; wa.W[3] = Wo;
    wa.Wt[0] = wqt; wa.Wt[1] = wkt; wa.Wt[2] = wvt; wa.Wt[3] = wot;
    cvt_wt_kernel<<<dim3(HD_ * HD_ / 256, 1, 4), 256, 0, stream>>>(wa);

    QKVArgs qa;
    qa.Bt[0] = wqt; qa.Bt[1] = wkt; qa.Bt[2] = wvt;
    qa.bias[0] = bq; qa.bias[1] = bk; qa.bias[2] = bv;
    qa.out[0] = qb; qa.out[1] = kfb; qa.out[2] = vfb;
    gemm_qkv_kernel<<<dim3(HD_ / 128, M_TOT / 128, 3), 256, 0, stream>>>(xb, qa);

    attn_kernel<<<dim3(LL / 128, NN * HH), 256, 0, stream>>>(qb, kfb, vfb, ob);

    gemm_o_kernel<<<dim3(HD_ / 128, M_TOT / 128), 256, 0, stream>>>(ob, wot, bo, (float*)d_out);
}